// Round 1
// baseline (111.994 us; speedup 1.0000x reference)
//
#include <hip/hip_runtime.h>
#include <stdint.h>

#define NBOX 8192

// ---------------------------------------------------------------------------
// Kernel 1: stable rank sort by descending score (ascending index on ties),
// then scatter boxes (+areas) into sorted SoA layout in workspace.
// key = (~score_bits << 32) | index  -> ascending u64 order == desired order.
// Each block stages all 8192 keys in LDS; 8 threads cooperate per element.
// ---------------------------------------------------------------------------
__global__ __launch_bounds__(256) void nms_rank_kernel(
    const float* __restrict__ bbox, const float* __restrict__ score,
    float* __restrict__ ws)
{
    __shared__ uint64_t keys[NBOX];          // 64 KB
    float* sy1 = ws;
    float* sx1 = ws + NBOX;
    float* sy2 = ws + 2 * NBOX;
    float* sx2 = ws + 3 * NBOX;
    float* sar = ws + 4 * NBOX;

    const int t = threadIdx.x;
    #pragma unroll
    for (int s = 0; s < NBOX / 256; ++s) {
        int i = t + s * 256;
        uint32_t b = __float_as_uint(score[i]);   // scores >= 0: bits monotone
        keys[i] = ((uint64_t)(b ^ 0xFFFFFFFFu) << 32) | (uint32_t)i;
    }
    __syncthreads();

    const int e = blockIdx.x * 32 + (t >> 3);  // element this 8-thread group owns
    const int p = t & 7;                       // sub-slice id
    const uint64_t myk = keys[e];
    int cnt = 0;
    const uint64_t* kp = keys + p * (NBOX / 8);
    #pragma unroll 8
    for (int s = 0; s < NBOX / 8; ++s)
        cnt += (kp[s] < myk) ? 1 : 0;

    cnt += __shfl_down(cnt, 4, 8);
    cnt += __shfl_down(cnt, 2, 8);
    cnt += __shfl_down(cnt, 1, 8);

    if (p == 0) {
        int r = cnt;                            // unique rank (keys are unique)
        float y1 = bbox[e * 4 + 0], x1 = bbox[e * 4 + 1];
        float y2 = bbox[e * 4 + 2], x2 = bbox[e * 4 + 3];
        sy1[r] = y1; sx1[r] = x1; sy2[r] = y2; sx2[r] = x2;
        sar[r] = (y2 - y1) * (x2 - x1);        // same op order as reference
    }
}

// ---------------------------------------------------------------------------
// Kernel 2: keep[j] = !any_{i<j} IoU(i,j) > 0.7 ; out[j] = keep ? box[j] : 0.
// One wave handles 4 consecutive sorted rows; lanes sweep i in chunks of 64.
// IoU replicated exactly in float32 (IEEE division) to match the reference.
// ---------------------------------------------------------------------------
__global__ __launch_bounds__(256) void nms_suppress_kernel(
    const float* __restrict__ ws, float* __restrict__ out)
{
    const float* sy1 = ws;
    const float* sx1 = ws + NBOX;
    const float* sy2 = ws + 2 * NBOX;
    const float* sx2 = ws + 3 * NBOX;
    const float* sar = ws + 4 * NBOX;

    const int wave = (int)((blockIdx.x * blockDim.x + threadIdx.x) >> 6);
    const int lane = (int)(threadIdx.x & 63);
    const int j0 = wave * 4;
    if (j0 >= NBOX) return;

    float jy1[4], jx1[4], jy2[4], jx2[4], jar[4];
    #pragma unroll
    for (int k = 0; k < 4; ++k) {
        int j = j0 + k;
        jy1[k] = sy1[j]; jx1[k] = sx1[j];
        jy2[k] = sy2[j]; jx2[k] = sx2[j];
        jar[k] = sar[j];
    }

    bool f0 = false, f1 = false, f2 = false, f3 = false;
    const int imax = j0 + 3;                 // largest needed i is j0+2
    for (int base = 0; base < imax; base += 64) {
        int i = base + lane;
        int ii = (i < imax) ? i : 0;
        float iy1 = sy1[ii], ix1 = sx1[ii];
        float iy2 = sy2[ii], ix2 = sx2[ii];
        float ia  = sar[ii];

        #pragma unroll
        for (int k = 0; k < 4; ++k) {
            float ty1 = fmaxf(iy1, jy1[k]);
            float tx1 = fmaxf(ix1, jx1[k]);
            float ty2 = fminf(iy2, jy2[k]);
            float tx2 = fminf(ix2, jx2[k]);
            float ih = fmaxf(ty2 - ty1, 0.0f);
            float iw = fmaxf(tx2 - tx1, 0.0f);
            float inter = ih * iw;
            float uni = ia + jar[k] - inter;
            float iou = inter / fmaxf(uni, 1e-9f);   // IEEE f32 div, as jnp
            bool hit = (i < j0 + k) & (iou > 0.7f);
            if (k == 0) f0 |= hit;
            else if (k == 1) f1 |= hit;
            else if (k == 2) f2 |= hit;
            else f3 |= hit;
        }
        // wave-uniform early exit once all 4 rows are known-suppressed
        if (__any(f0) && __any(f1) && __any(f2) && __any(f3)) break;
    }

    int s0 = __any(f0), s1 = __any(f1), s2 = __any(f2), s3 = __any(f3);
    if (lane < 16) {
        int k = lane >> 2, c = lane & 3;
        int j = j0 + k;
        int sup = (k == 0) ? s0 : (k == 1) ? s1 : (k == 2) ? s2 : s3;
        const float* arr = (c == 0) ? sy1 : (c == 1) ? sx1 : (c == 2) ? sy2 : sx2;
        float v = arr[j];
        out[j * 4 + c] = sup ? 0.0f : v;
    }
}

extern "C" void kernel_launch(void* const* d_in, const int* in_sizes, int n_in,
                              void* d_out, int out_size, void* d_ws, size_t ws_size,
                              hipStream_t stream) {
    const float* bbox  = (const float*)d_in[0];   // (8192,4) f32
    const float* score = (const float*)d_in[1];   // (8192,)  f32
    float* out = (float*)d_out;                   // (8192,4) f32
    float* ws  = (float*)d_ws;                    // needs 5*8192*4 = 160 KB

    hipLaunchKernelGGL(nms_rank_kernel, dim3(NBOX / 32), dim3(256), 0, stream,
                       bbox, score, ws);
    hipLaunchKernelGGL(nms_suppress_kernel, dim3((NBOX / 4) / 4), dim3(256), 0, stream,
                       ws, out);
}

// Round 2
// 52.004 us; speedup vs baseline: 2.1536x; 2.1536x over previous
//
#include <hip/hip_runtime.h>
#include <stdint.h>

#define NBOX 8192

// ws layout (floats): sy1[N], sx1[N], sy2[N], sx2[N], then flags = 256 u32 (1 KB)
// total 128 KB + 1 KB, well under the 160 KB proven available in round 1.

// ---------------------------------------------------------------------------
// Kernel 1: stable rank by (desc score, asc index); scatter boxes to sorted
// SoA in ws; zero the suppress-flag bitmap.
// key = (~score_bits << 32) | index  -> ascending u64 == desired order.
// 16 threads/element, interleaved LDS slices (conflict-free, broadcast-8).
// ---------------------------------------------------------------------------
__global__ __launch_bounds__(256) void nms_rank_kernel(
    const float* __restrict__ bbox, const float* __restrict__ score,
    float* __restrict__ ws)
{
    __shared__ uint64_t keys[NBOX];          // 64 KB
    float* sy1 = ws;
    float* sx1 = ws + NBOX;
    float* sy2 = ws + 2 * NBOX;
    float* sx2 = ws + 3 * NBOX;
    uint32_t* flags = (uint32_t*)(ws + 4 * NBOX);   // 256 words

    const int t = threadIdx.x;
    if (blockIdx.x == 0) flags[t] = 0;       // 256 words zeroed by block 0

    #pragma unroll
    for (int s = 0; s < NBOX / 256; ++s) {
        int i = t + s * 256;
        uint32_t b = __float_as_uint(score[i]);   // scores in [0,1): bits monotone
        keys[i] = ((uint64_t)(b ^ 0xFFFFFFFFu) << 32) | (uint32_t)i;
    }
    __syncthreads();

    const int e = blockIdx.x * 16 + (t >> 4);  // element this 16-thread group owns
    const int p = t & 15;                      // sub-slice id
    const uint64_t myk = keys[e];
    int cnt = 0;
    // interleaved: thread p scans s*16+p -> 128 contiguous bytes per wave-iter,
    // same-p lanes broadcast, no bank conflicts.
    #pragma unroll 8
    for (int s = 0; s < NBOX / 16; ++s)
        cnt += (keys[s * 16 + p] < myk) ? 1 : 0;

    cnt += __shfl_down(cnt, 8, 16);
    cnt += __shfl_down(cnt, 4, 16);
    cnt += __shfl_down(cnt, 2, 16);
    cnt += __shfl_down(cnt, 1, 16);

    if (p == 0) {
        int r = cnt;                            // unique rank (keys unique)
        sy1[r] = bbox[e * 4 + 0];
        sx1[r] = bbox[e * 4 + 1];
        sy2[r] = bbox[e * 4 + 2];
        sx2[r] = bbox[e * 4 + 3];
    }
}

// ---------------------------------------------------------------------------
// Kernel 2: balanced suppression. Task = (jg: group of 8 sorted rows) x
// (is: 512-wide i-slice). One wave per task; ~half the rectangle early-exits.
// Pre-filter inter > 0.6999*union (never misses a true hit); exact IEEE f32
// div only for rare candidates. Suppressed rows -> atomicOr into bitmap.
// ---------------------------------------------------------------------------
__global__ __launch_bounds__(256) void nms_suppress_kernel(float* __restrict__ ws)
{
    const float* sy1 = ws;
    const float* sx1 = ws + NBOX;
    const float* sy2 = ws + 2 * NBOX;
    const float* sx2 = ws + 3 * NBOX;
    uint32_t* flags = (uint32_t*)(ws + 4 * NBOX);

    const int wid  = (int)((blockIdx.x * blockDim.x + threadIdx.x) >> 6);
    const int lane = (int)(threadIdx.x & 63);
    const int jg = wid >> 4;           // 0..1023 : rows [jg*8, jg*8+8)
    const int is = wid & 15;           // 0..15   : i in [is*512, is*512+512)
    const int j0 = jg * 8;
    if (is * 512 >= j0 + 7) return;    // no i < j anywhere in this slice

    float jy1[8], jx1[8], jy2[8], jx2[8], ja[8];
    #pragma unroll
    for (int k = 0; k < 8; ++k) {
        int j = j0 + k;
        jy1[k] = sy1[j]; jx1[k] = sx1[j];
        jy2[k] = sy2[j]; jx2[k] = sx2[j];
        ja[k] = (jy2[k] - jy1[k]) * (jx2[k] - jx1[k]);  // same op order as ref
    }

    uint32_t hit = 0;
    #pragma unroll 2
    for (int c = 0; c < 8; ++c) {
        int ibase = is * 512 + c * 64;
        if (ibase >= j0 + 7) break;    // wave-uniform diagonal prune
        int i = ibase + lane;          // always < 8192
        float iy1 = sy1[i], ix1 = sx1[i], iy2 = sy2[i], ix2 = sx2[i];
        float ia = (iy2 - iy1) * (ix2 - ix1);

        float inter[8], uni[8];
        uint32_t cand = 0;
        #pragma unroll
        for (int k = 0; k < 8; ++k) {
            float ty1 = fmaxf(iy1, jy1[k]);
            float tx1 = fmaxf(ix1, jx1[k]);
            float ty2 = fminf(iy2, jy2[k]);
            float tx2 = fminf(ix2, jx2[k]);
            float ih = fmaxf(ty2 - ty1, 0.0f);
            float iw = fmaxf(tx2 - tx1, 0.0f);
            float in_ = ih * iw;
            float un  = ia + ja[k] - in_;
            inter[k] = in_; uni[k] = un;
            if ((in_ > 0.6999f * un) & (i < j0 + k)) cand |= (1u << k);
        }
        if (cand) {                    // rare: exact IEEE f32 check
            #pragma unroll
            for (int k = 0; k < 8; ++k) {
                if (cand & (1u << k)) {
                    float iou = inter[k] / fmaxf(uni[k], 1e-9f);
                    if (iou > 0.7f) hit |= (1u << k);
                }
            }
        }
    }

    uint32_t byte = 0;
    #pragma unroll
    for (int k = 0; k < 8; ++k)
        if (__any(hit & (1u << k))) byte |= (1u << k);
    if (lane == 0 && byte)
        atomicOr(&flags[jg >> 2], byte << ((jg & 3) * 8));
}

// ---------------------------------------------------------------------------
// Kernel 3: masked write. out[j] = suppressed ? 0 : sorted_box[j], as float4.
// ---------------------------------------------------------------------------
__global__ __launch_bounds__(256) void nms_write_kernel(
    const float* __restrict__ ws, float* __restrict__ out)
{
    const float* sy1 = ws;
    const float* sx1 = ws + NBOX;
    const float* sy2 = ws + 2 * NBOX;
    const float* sx2 = ws + 3 * NBOX;
    const uint32_t* flags = (const uint32_t*)(ws + 4 * NBOX);

    int j = blockIdx.x * 256 + threadIdx.x;
    bool sup = (flags[j >> 5] >> (j & 31)) & 1u;
    float4 v;
    v.x = sup ? 0.0f : sy1[j];
    v.y = sup ? 0.0f : sx1[j];
    v.z = sup ? 0.0f : sy2[j];
    v.w = sup ? 0.0f : sx2[j];
    ((float4*)out)[j] = v;
}

extern "C" void kernel_launch(void* const* d_in, const int* in_sizes, int n_in,
                              void* d_out, int out_size, void* d_ws, size_t ws_size,
                              hipStream_t stream) {
    const float* bbox  = (const float*)d_in[0];   // (8192,4) f32
    const float* score = (const float*)d_in[1];   // (8192,)  f32
    float* out = (float*)d_out;                   // (8192,4) f32
    float* ws  = (float*)d_ws;                    // 128 KB + 1 KB flags

    hipLaunchKernelGGL(nms_rank_kernel, dim3(NBOX / 16), dim3(256), 0, stream,
                       bbox, score, ws);
    // 1024 row-groups x 16 slices = 16384 waves = 4096 blocks of 4 waves
    hipLaunchKernelGGL(nms_suppress_kernel, dim3(4096), dim3(256), 0, stream, ws);
    hipLaunchKernelGGL(nms_write_kernel, dim3(NBOX / 256), dim3(256), 0, stream,
                       ws, out);
}

// Round 3
// 36.410 us; speedup vs baseline: 3.0759x; 1.4283x over previous
//
#include <hip/hip_runtime.h>
#include <stdint.h>

#define NBOX 8192

// ws layout: float4 sbox[8192] (128 KB) then uint32_t flags[256] (1 KB).

// ---------------------------------------------------------------------------
// Kernel 1: stable rank by (desc score, asc index); scatter boxes as float4
// into sorted order; block 0 zeroes the suppress-flag bitmap.
// key = (~score_bits << 32) | index  -> ascending u64 == desired order.
// ---------------------------------------------------------------------------
__global__ __launch_bounds__(256) void nms_rank_kernel(
    const float4* __restrict__ bbox, const float* __restrict__ score,
    float4* __restrict__ sbox, uint32_t* __restrict__ flags)
{
    __shared__ uint64_t keys[NBOX];          // 64 KB
    const int t = threadIdx.x;
    if (blockIdx.x == 0) flags[t] = 0;       // 256 words

    #pragma unroll
    for (int s = 0; s < NBOX / 256; ++s) {
        int i = t + s * 256;
        uint32_t b = __float_as_uint(score[i]);   // scores in [0,1): bits monotone
        keys[i] = ((uint64_t)(b ^ 0xFFFFFFFFu) << 32) | (uint32_t)i;
    }
    __syncthreads();

    const int e = blockIdx.x * 16 + (t >> 4);  // element this 16-thread group owns
    const int p = t & 15;
    const uint64_t myk = keys[e];
    int cnt = 0;
    // interleaved slices: contiguous 128B per wave-iter, broadcast across same-p
    #pragma unroll 8
    for (int s = 0; s < NBOX / 16; ++s)
        cnt += (keys[s * 16 + p] < myk) ? 1 : 0;

    cnt += __shfl_down(cnt, 8, 16);
    cnt += __shfl_down(cnt, 4, 16);
    cnt += __shfl_down(cnt, 2, 16);
    cnt += __shfl_down(cnt, 1, 16);

    if (p == 0) sbox[cnt] = bbox[e];           // unique rank, one dwordx4 store
}

// ---------------------------------------------------------------------------
// Kernel 2: suppression. Wave task = (jg: 8 sorted rows) x (is: 512-wide
// i-slice). Block's 4 waves share the i-slice (L1 reuse), consecutive jg.
// Full chunks (all i < j0): no per-pair mask. Register-double-buffered
// prefetch of the next chunk. Division-free conservative prefilter
// inter > 0.4110*(ai+aj); exact IEEE f32 div only for rare candidates.
// ---------------------------------------------------------------------------
__global__ __launch_bounds__(256) void nms_suppress_kernel(
    const float4* __restrict__ sbox, uint32_t* __restrict__ flags)
{
    const int w    = (int)(threadIdx.x >> 6);
    const int lane = (int)(threadIdx.x & 63);
    const int is   = (int)(blockIdx.x >> 8);            // 0..15
    const int jg   = ((int)(blockIdx.x & 255)) * 4 + w; // 0..1023
    const int j0   = jg * 8;
    const int s0   = is * 512;
    if (s0 >= j0 + 7) return;                 // slice entirely above diagonal

    int nfull = (j0 - s0) >> 6;               // chunks with all i < j0
    if (nfull < 0) nfull = 0;
    if (nfull > 8) nfull = 8;
    const int pc = nfull;                      // diagonal (masked) chunk index
    const bool partial = (pc < 8) && (s0 + pc * 64 < j0 + 7);

    float jy1[8], jx1[8], jy2[8], jx2[8], ja[8];
    #pragma unroll
    for (int k = 0; k < 8; ++k) {
        float4 b = sbox[j0 + k];
        jy1[k] = b.x; jx1[k] = b.y; jy2[k] = b.z; jx2[k] = b.w;
        ja[k] = (b.z - b.x) * (b.w - b.y);     // same fp op order as reference
    }

    uint32_t hit = 0;
    // chunk 0 (also the partial chunk when nfull==0); always in-bounds
    float4 cur = sbox[s0 + lane];

    for (int c = 0; c < nfull; ++c) {
        // prefetch chunk c+1; s0+(c+1)*64 is a 64-multiple <= j0 <= 8184,
        // hence <= 8128, so s0+(c+1)*64+lane <= 8191: in-bounds.
        float4 nxt = sbox[s0 + (c + 1) * 64 + lane];

        const float iy1 = cur.x, ix1 = cur.y, iy2 = cur.z, ix2 = cur.w;
        const float ia = (iy2 - iy1) * (ix2 - ix1);
        #pragma unroll
        for (int k = 0; k < 8; ++k) {
            float ty1 = fmaxf(iy1, jy1[k]);
            float tx1 = fmaxf(ix1, jx1[k]);
            float ty2 = fminf(iy2, jy2[k]);
            float tx2 = fminf(ix2, jx2[k]);
            float ih = fmaxf(ty2 - ty1, 0.0f);
            float iw = fmaxf(tx2 - tx1, 0.0f);
            float inter = ih * iw;
            float s = ia + ja[k];
            if (inter > 0.4110f * s) {         // conservative: 0.7/1.7=0.41176
                float un = s - inter;          // == fl(fl(ai+aj)-inter), as ref
                float iou = inter / fmaxf(un, 1e-9f);
                if (iou > 0.7f) hit |= (1u << k);
            }
        }
        cur = nxt;
    }

    if (partial) {                             // cur holds chunk pc
        const int i = s0 + pc * 64 + lane;     // <= 8191 (see bound above)
        const float iy1 = cur.x, ix1 = cur.y, iy2 = cur.z, ix2 = cur.w;
        const float ia = (iy2 - iy1) * (ix2 - ix1);
        #pragma unroll
        for (int k = 0; k < 8; ++k) {
            float ty1 = fmaxf(iy1, jy1[k]);
            float tx1 = fmaxf(ix1, jx1[k]);
            float ty2 = fminf(iy2, jy2[k]);
            float tx2 = fminf(ix2, jx2[k]);
            float ih = fmaxf(ty2 - ty1, 0.0f);
            float iw = fmaxf(tx2 - tx1, 0.0f);
            float inter = ih * iw;
            float s = ia + ja[k];
            if ((i < j0 + k) & (inter > 0.4110f * s)) {
                float un = s - inter;
                float iou = inter / fmaxf(un, 1e-9f);
                if (iou > 0.7f) hit |= (1u << k);
            }
        }
    }

    uint32_t byte = 0;
    #pragma unroll
    for (int k = 0; k < 8; ++k)
        if (__any(hit & (1u << k))) byte |= (1u << k);
    if (lane == 0 && byte)
        atomicOr(&flags[jg >> 2], byte << ((jg & 3) * 8));
}

// ---------------------------------------------------------------------------
// Kernel 3: masked float4 write of sorted boxes.
// ---------------------------------------------------------------------------
__global__ __launch_bounds__(256) void nms_write_kernel(
    const float4* __restrict__ sbox, const uint32_t* __restrict__ flags,
    float4* __restrict__ out)
{
    int j = blockIdx.x * 256 + threadIdx.x;
    bool sup = (flags[j >> 5] >> (j & 31)) & 1u;
    float4 v = sbox[j];
    if (sup) { v.x = 0.0f; v.y = 0.0f; v.z = 0.0f; v.w = 0.0f; }
    out[j] = v;
}

extern "C" void kernel_launch(void* const* d_in, const int* in_sizes, int n_in,
                              void* d_out, int out_size, void* d_ws, size_t ws_size,
                              hipStream_t stream) {
    const float4* bbox  = (const float4*)d_in[0];   // (8192,4) f32
    const float*  score = (const float*)d_in[1];    // (8192,)  f32
    float4* out = (float4*)d_out;                   // (8192,4) f32
    float4* sbox = (float4*)d_ws;                   // 128 KB
    uint32_t* flags = (uint32_t*)((float*)d_ws + 4 * NBOX);  // 1 KB

    hipLaunchKernelGGL(nms_rank_kernel, dim3(NBOX / 16), dim3(256), 0, stream,
                       bbox, score, sbox, flags);
    // 16 i-slices x 256 jg-quads = 4096 blocks; block's 4 waves share a slice
    hipLaunchKernelGGL(nms_suppress_kernel, dim3(4096), dim3(256), 0, stream,
                       sbox, flags);
    hipLaunchKernelGGL(nms_write_kernel, dim3(NBOX / 256), dim3(256), 0, stream,
                       sbox, flags, out);
}